// Round 3
// baseline (1319.452 us; speedup 1.0000x reference)
//
#include <hip/hip_runtime.h>
#include <math.h>

#define N_NODES 100000
#define N_EDGES 3200000
#define FIN     1433

// ---------------- zero ----------------
__global__ void k_zero(int* __restrict__ p, int n) {
  int i = blockIdx.x * blockDim.x + threadIdx.x;
  if (i < n) p[i] = 0;
}

// ---------------- histogram of destinations (4 edges/thread) ----------------
__global__ void k_hist(const int4* __restrict__ row4, int* __restrict__ cnt) {
  int i = blockIdx.x * blockDim.x + threadIdx.x;
  if (i < N_EDGES / 4) {
    int4 r = row4[i];
    atomicAdd(&cnt[r.x], 1);
    atomicAdd(&cnt[r.y], 1);
    atomicAdd(&cnt[r.z], 1);
    atomicAdd(&cnt[r.w], 1);
  }
}

// ---------------- 3-phase exclusive scan (1024 elems/block) ----------------
__global__ void k_scanA(const int* __restrict__ cnt, int* __restrict__ bsum) {
  __shared__ int sd[256];
  int t = threadIdx.x, b = blockIdx.x;
  int base = b * 1024 + t * 4;
  int s = 0;
#pragma unroll
  for (int m = 0; m < 4; m++) {
    int i = base + m;
    if (i < N_NODES) s += cnt[i];
  }
  sd[t] = s; __syncthreads();
  for (int off = 128; off > 0; off >>= 1) {
    if (t < off) sd[t] += sd[t + off];
    __syncthreads();
  }
  if (t == 0) bsum[b] = sd[0];
}

__global__ void k_scanB(int* __restrict__ bsum, int* __restrict__ rowStart, int nb) {
  __shared__ int sd[128];
  int t = threadIdx.x;
  int v = (t < nb) ? bsum[t] : 0;
  sd[t] = v;
  __syncthreads();
  for (int off = 1; off < 128; off <<= 1) {
    int add = (t >= off) ? sd[t - off] : 0;
    __syncthreads();
    sd[t] += add;
    __syncthreads();
  }
  if (t < nb) bsum[t] = (t == 0) ? 0 : sd[t - 1];
  if (t == 0) rowStart[N_NODES] = sd[nb - 1];
}

// scanC also initializes fillpos (=rowStart) and dinv (fused)
__global__ void k_scanC(const int* __restrict__ cnt, const int* __restrict__ bsum,
                        int* __restrict__ rowStart, int* __restrict__ fillpos,
                        float* __restrict__ dinv) {
  __shared__ int sd[256];
  int t = threadIdx.x, b = blockIdx.x;
  int base = b * 1024 + t * 4;
  int v[4], pre[4], s = 0;
#pragma unroll
  for (int m = 0; m < 4; m++) {
    int i = base + m;
    v[m] = (i < N_NODES) ? cnt[i] : 0;
    pre[m] = s; s += v[m];
  }
  sd[t] = s; __syncthreads();
  for (int off = 1; off < 256; off <<= 1) {
    int add = (t >= off) ? sd[t - off] : 0;
    __syncthreads();
    sd[t] += add;
    __syncthreads();
  }
  int ex = (t == 0) ? 0 : sd[t - 1];
  int base0 = bsum[b] + ex;
#pragma unroll
  for (int m = 0; m < 4; m++) {
    int i = base + m;
    if (i < N_NODES) {
      int rs = base0 + pre[m];
      rowStart[i] = rs;
      fillpos[i]  = rs;
      dinv[i] = 1.0f / sqrtf((float)(v[m] + 1));
    }
  }
}

// ---------------- scatter edges into CSR (4 edges/thread) ----------------
__global__ void k_scatter(const int4* __restrict__ row4, const int4* __restrict__ col4,
                          int* __restrict__ fillpos, int* __restrict__ colc) {
  int i = blockIdx.x * blockDim.x + threadIdx.x;
  if (i < N_EDGES / 4) {
    int4 r = row4[i];
    int4 c = col4[i];
    int p0 = atomicAdd(&fillpos[r.x], 1); colc[p0] = c.x;
    int p1 = atomicAdd(&fillpos[r.y], 1); colc[p1] = c.y;
    int p2 = atomicAdd(&fillpos[r.z], 1); colc[p2] = c.z;
    int p3 = atomicAdd(&fillpos[r.w], 1); colc[p3] = c.w;
  }
}

// ---------------- GEMM1: t1s = dinv .* (x @ W1)  (100000x1433 @ 1433x16) ----
// Thread-per-row, register double-buffered streaming (8 float4 loads in
// flight while 512 FMAs execute). W1 lane-uniform -> scalar loads.
__global__ __launch_bounds__(64) void k_gemm1(const float* __restrict__ x,
                                              const float* __restrict__ W1,
                                              const float* __restrict__ dinv,
                                              float* __restrict__ t1s) {
  int rowi = blockIdx.x * 64 + threadIdx.x;
  if (rowi >= N_NODES) return;
  const float* __restrict__ xr = x + (size_t)rowi * FIN;

  float acc[16];
#pragma unroll
  for (int j = 0; j < 16; j++) acc[j] = 0.0f;

  float4 buf[8], nbuf[8];
#pragma unroll
  for (int m = 0; m < 8; m++) buf[m] = *(const float4*)(xr + m * 4);

  const int NCH = 44;  // 44*32 = 1408
  for (int ch = 0; ch < NCH; ch++) {
    int kc = ch * 32;
    if (ch + 1 < NCH) {
#pragma unroll
      for (int m = 0; m < 8; m++) nbuf[m] = *(const float4*)(xr + kc + 32 + m * 4);
    }
#pragma unroll
    for (int m = 0; m < 8; m++) {
      float xv0 = buf[m].x, xv1 = buf[m].y, xv2 = buf[m].z, xv3 = buf[m].w;
      const float* w0 = &W1[(size_t)(kc + m * 4 + 0) * 16];
      const float* w1 = &W1[(size_t)(kc + m * 4 + 1) * 16];
      const float* w2 = &W1[(size_t)(kc + m * 4 + 2) * 16];
      const float* w3 = &W1[(size_t)(kc + m * 4 + 3) * 16];
#pragma unroll
      for (int j = 0; j < 16; j++) {
        acc[j] = fmaf(xv0, w0[j], acc[j]);
        acc[j] = fmaf(xv1, w1[j], acc[j]);
        acc[j] = fmaf(xv2, w2[j], acc[j]);
        acc[j] = fmaf(xv3, w3[j], acc[j]);
      }
    }
#pragma unroll
    for (int m = 0; m < 8; m++) buf[m] = nbuf[m];
  }
  for (int k = 1408; k < FIN; k++) {
    float xv = xr[k];
    const float* w = &W1[(size_t)k * 16];
#pragma unroll
    for (int j = 0; j < 16; j++) acc[j] = fmaf(xv, w[j], acc[j]);
  }

  float di = dinv[rowi];
  float* o = t1s + (size_t)rowi * 16;
#pragma unroll
  for (int j = 0; j < 16; j += 4)
    *(float4*)(o + j) = make_float4(di * acc[j], di * acc[j + 1],
                                    di * acc[j + 2], di * acc[j + 3]);
}

// ---------------- agg1 fused with gemm2:
// h = relu(di*(sum_c t1s[c] + t1s[i]) + b1);  t2s[i] = di * (h @ W2)  (padded 8)
// Wave per node; 4 lanes per edge slice, 16 edge slots.
__global__ __launch_bounds__(256) void k_agg1(const float* __restrict__ t1s,
                                              const int* __restrict__ rowStart,
                                              const int* __restrict__ colc,
                                              const float* __restrict__ dinv,
                                              const float* __restrict__ b1,
                                              const float* __restrict__ W2,
                                              float* __restrict__ t2s) {
  int lane = threadIdx.x & 63;
  int wid  = threadIdx.x >> 6;
  int node = blockIdx.x * 4 + wid;
  if (node >= N_NODES) return;
  int q = lane & 3, slot = lane >> 2;
  int s0 = rowStart[node], s1 = rowStart[node + 1];
  float ax = 0.f, ay = 0.f, az = 0.f, aw = 0.f;
  for (int e = s0 + slot; e < s1; e += 16) {
    int c = colc[e];
    float4 v = *(const float4*)(t1s + (size_t)c * 16 + q * 4);
    ax += v.x; ay += v.y; az += v.z; aw += v.w;
  }
#pragma unroll
  for (int off = 4; off < 64; off <<= 1) {
    ax += __shfl_xor(ax, off, 64);
    ay += __shfl_xor(ay, off, 64);
    az += __shfl_xor(az, off, 64);
    aw += __shfl_xor(aw, off, 64);
  }
  float di = dinv[node];
  if (slot == 0) {  // lanes 0..3
    float4 sv = *(const float4*)(t1s + (size_t)node * 16 + q * 4);
    float4 bb = *(const float4*)(b1 + q * 4);
    float h0 = fmaxf(0.f, di * (ax + sv.x) + bb.x);
    float h1 = fmaxf(0.f, di * (ay + sv.y) + bb.y);
    float h2 = fmaxf(0.f, di * (az + sv.z) + bb.z);
    float h3 = fmaxf(0.f, di * (aw + sv.w) + bb.w);
    // partial of h @ W2 over rows 4q..4q+3
    float p[8];
#pragma unroll
    for (int j = 0; j < 8; j++) p[j] = 0.f;
    const float* w = W2 + q * 4 * 7;
#pragma unroll
    for (int j = 0; j < 7; j++)
      p[j] = h0 * w[j] + h1 * w[7 + j] + h2 * w[14 + j] + h3 * w[21 + j];
    // reduce across the 4 q-lanes (lanes 0..3)
#pragma unroll
    for (int off = 1; off < 4; off <<= 1) {
#pragma unroll
      for (int j = 0; j < 7; j++) p[j] += __shfl_xor(p[j], off, 64);
    }
    if (q < 2) {
      float4 o;
      o.x = di * p[q * 4 + 0];
      o.y = di * p[q * 4 + 1];
      o.z = di * p[q * 4 + 2];
      o.w = di * p[q * 4 + 3];
      *(float4*)(t2s + (size_t)node * 8 + q * 4) = o;
    }
  }
}

// ---------------- agg2 + bias + log_softmax -> out ----------------
// out[i] = log_softmax(di*(sum_c t2s[c] + t2s[i]) + b2)
__global__ __launch_bounds__(256) void k_agg2(const float* __restrict__ t2s,
                                              const int* __restrict__ rowStart,
                                              const int* __restrict__ colc,
                                              const float* __restrict__ dinv,
                                              const float* __restrict__ b2,
                                              float* __restrict__ out) {
  int lane = threadIdx.x & 63;
  int wid  = threadIdx.x >> 6;
  int node = blockIdx.x * 4 + wid;
  if (node >= N_NODES) return;
  int q = lane & 1, slot = lane >> 1;
  int s0 = rowStart[node], s1 = rowStart[node + 1];
  float ax = 0.f, ay = 0.f, az = 0.f, aw = 0.f;
  for (int e = s0 + slot; e < s1; e += 32) {
    int c = colc[e];
    float4 v = *(const float4*)(t2s + (size_t)c * 8 + q * 4);
    ax += v.x; ay += v.y; az += v.z; aw += v.w;
  }
#pragma unroll
  for (int off = 2; off < 64; off <<= 1) {
    ax += __shfl_xor(ax, off, 64);
    ay += __shfl_xor(ay, off, 64);
    az += __shfl_xor(az, off, 64);
    aw += __shfl_xor(aw, off, 64);
  }
  float di = dinv[node];
  float4 sv = *(const float4*)(t2s + (size_t)node * 8 + q * 4);
  float lg[4];
  float am[4] = {ax, ay, az, aw};
  float sm[4] = {sv.x, sv.y, sv.z, sv.w};
#pragma unroll
  for (int m = 0; m < 4; m++) {
    int j = 4 * q + m;
    float bb = (j < 7) ? b2[j] : 0.0f;
    lg[m] = di * (am[m] + sm[m]) + bb;
    if (j == 7) lg[m] = -1e30f;
  }
  float o4 = __shfl_xor(lg[0], 1, 64);
  float o5 = __shfl_xor(lg[1], 1, 64);
  float o6 = __shfl_xor(lg[2], 1, 64);
  if (lane == 0) {
    float a[7] = {lg[0], lg[1], lg[2], lg[3], o4, o5, o6};
    float mx = a[0];
#pragma unroll
    for (int j = 1; j < 7; j++) mx = fmaxf(mx, a[j]);
    float s = 0.f;
#pragma unroll
    for (int j = 0; j < 7; j++) s += expf(a[j] - mx);
    float lse = mx + logf(s);
    float* o = out + (size_t)node * 7;
#pragma unroll
    for (int j = 0; j < 7; j++) o[j] = a[j] - lse;
  }
}

extern "C" void kernel_launch(void* const* d_in, const int* in_sizes, int n_in,
                              void* d_out, int out_size, void* d_ws, size_t ws_size,
                              hipStream_t stream) {
  const float* x   = (const float*)d_in[0];
  const int*   row = (const int*)d_in[1];
  const int*   col = (const int*)d_in[2];
  const float* W1  = (const float*)d_in[3];
  const float* b1  = (const float*)d_in[4];
  const float* W2  = (const float*)d_in[5];
  const float* b2  = (const float*)d_in[6];
  float* out = (float*)d_out;

  char* w = (char*)d_ws;
  auto alloc = [&](size_t bytes) {
    char* p = w;
    w += (bytes + 255) & ~(size_t)255;
    return p;
  };
  int*   cnt      = (int*)alloc((size_t)N_NODES * 4);
  int*   fillpos  = (int*)alloc((size_t)N_NODES * 4);
  int*   rowStart = (int*)alloc((size_t)(N_NODES + 1) * 4);
  int*   bsum     = (int*)alloc(128 * 4);
  float* dinv     = (float*)alloc((size_t)N_NODES * 4);
  int*   colc     = (int*)alloc((size_t)N_EDGES * 4);
  float* t1s      = (float*)alloc((size_t)N_NODES * 16 * 4);
  float* t2s      = (float*)alloc((size_t)N_NODES * 8 * 4);

  const int NB = (N_NODES + 1023) / 1024;  // 98
  const int E4 = N_EDGES / 4;              // 800000

  k_zero<<<(N_NODES + 255) / 256, 256, 0, stream>>>(cnt, N_NODES);
  k_hist<<<(E4 + 255) / 256, 256, 0, stream>>>((const int4*)row, cnt);
  k_scanA<<<NB, 256, 0, stream>>>(cnt, bsum);
  k_scanB<<<1, 128, 0, stream>>>(bsum, rowStart, NB);
  k_scanC<<<NB, 256, 0, stream>>>(cnt, bsum, rowStart, fillpos, dinv);
  k_scatter<<<(E4 + 255) / 256, 256, 0, stream>>>((const int4*)row, (const int4*)col,
                                                  fillpos, colc);
  k_gemm1<<<(N_NODES + 63) / 64, 64, 0, stream>>>(x, W1, dinv, t1s);
  k_agg1<<<(N_NODES + 3) / 4, 256, 0, stream>>>(t1s, rowStart, colc, dinv, b1, W2, t2s);
  k_agg2<<<(N_NODES + 3) / 4, 256, 0, stream>>>(t2s, rowStart, colc, dinv, b2, out);
}